// Round 1
// baseline (9377.257 us; speedup 1.0000x reference)
//
#include <hip/hip_runtime.h>
#include <hip/hip_cooperative_groups.h>
#include <math.h>

namespace cg = cooperative_groups;

#define H 1024
#define L_ENC 128
#define V 50257
#define STEPS 32
#define STOP_ID 658

// ---- workspace layout (float offsets) ----
#define WS_H     0        // 1024  h buffer 0 (coop: ping-pong buf0)
#define WS_HNEW  1024     // 1024  h_new (coop: ping-pong buf1)
#define WS_GH    2048     // 3072  gh = h @ whh.T + bhh
#define WS_ALOG  5120     // 128   attention logits
#define WS_X     5248     // 1024  x = relu(comb)
#define WS_PMAX  6272     // fallback path: per-block argmax value
#define WS_PIDX  6784     // fallback path: per-block argmax index
#define WS_TOK   7296     // fallback path: current token
#define WS_DONE  7297     // fallback path: done flag
#define WS_PACK  6272     // coop path: 2 x u64 packed argmax slots (byte 25088, 8B aligned)

#define NB_OUT 508
#define NBLK   512
#define NWAVE  (NBLK * 4)

// ============================================================================
// Persistent cooperative kernel: all 32 decode steps, 4 grid syncs per step.
// Numerics: every dot/softmax/gate computation keeps the exact FP op order of
// the previous (passing) multi-kernel version -> bit-identical h and logits.
// Argmax: packed u64 (monotone float key << 32 | ~idx) + atomicMax — exact,
// order-independent, same max-then-lowest-index tie-break as jnp.argmax.
// ============================================================================
__global__ __launch_bounds__(256, 2) void k_decode(
    const int* __restrict__ dec_in, const float* __restrict__ h0,
    const float* __restrict__ enc, const float* __restrict__ embedding,
    const float* __restrict__ attn_w, const float* __restrict__ attn_b,
    const float* __restrict__ comb_w, const float* __restrict__ comb_b,
    const float* __restrict__ wih, const float* __restrict__ whh,
    const float* __restrict__ bih, const float* __restrict__ bhh,
    const float* __restrict__ out_w, const float* __restrict__ out_b,
    float* __restrict__ ws, int* __restrict__ out)
{
    cg::grid_group grid = cg::this_grid();
    const int t = threadIdx.x, wave = t >> 6, lane = t & 63;
    const int blk = blockIdx.x;
    const int gwave = blk * 4 + wave;

    __shared__ float s_aw[L_ENC];
    __shared__ __align__(16) float s_cat[2048];   // P2: cat; P3: x stage; P4: h stage
    __shared__ unsigned long long s_best[4];
    __shared__ int s_tok, s_done, s_cur;          // replicated per block, identical values

    unsigned long long* const pack = (unsigned long long*)(ws + WS_PACK);

    // ---- init ----
    if (t == 0) { s_tok = dec_in[0]; s_done = 0; s_cur = 0; }
    if (blk == 0) {
        for (int j = t; j < H; j += 256) ws[WS_H + j] = h0[j];
        if (t == 0) { pack[0] = 0ULL; pack[1] = 0ULL; }
    }
    __syncthreads();
    grid.sync();

    for (int step = 0; step < STEPS; ++step) {
        const int tok = s_tok;
        const float* hb   = ws + (s_cur ? WS_HNEW : WS_H);   // current h
        float*       hnew = ws + (s_cur ? WS_H : WS_HNEW);   // candidate slot
        const float4* h4 = (const float4*)hb;
        const float4* e4 = (const float4*)(embedding + (size_t)tok * H);

        // ---- P1: attention logits (tasks 0..127) + gh rows (tasks 128..3199) ----
        for (int task = gwave; task < 3200; task += NWAVE) {
            if (task < 128) {
                const int r = task;
                const float4* w4 = (const float4*)(attn_w + (size_t)r * 2048);
                float s = 0.f;
                for (int m = 0; m < 8; ++m) {
                    int j = lane + (m << 6);
                    float4 a = w4[j];
                    float4 c = (j < 256) ? e4[j] : h4[j - 256];
                    s += a.x * c.x + a.y * c.y + a.z * c.z + a.w * c.w;
                }
                for (int o = 32; o; o >>= 1) s += __shfl_down(s, o);
                if (lane == 0) ws[WS_ALOG + r] = s + attn_b[r];
            } else {
                const int r = task - 128;
                const float4* w4 = (const float4*)(whh + (size_t)r * H);
                float s = 0.f;
                for (int m = 0; m < 4; ++m) {
                    int j = lane + (m << 6);
                    float4 a = w4[j], b = h4[j];
                    s += a.x * b.x + a.y * b.y + a.z * b.z + a.w * b.w;
                }
                for (int o = 32; o; o >>= 1) s += __shfl_down(s, o);
                if (lane == 0) ws[WS_GH + r] = s + bhh[r];
            }
        }
        grid.sync();                                         // sync 1

        // ---- P2: softmax + ctx + comb -> x (blocks 0..63, 16 rows each) ----
        if (blk < 64) {
            if (t < L_ENC) s_aw[t] = ws[WS_ALOG + t];
            __syncthreads();
            float mx = -INFINITY;
            for (int l = 0; l < L_ENC; ++l) mx = fmaxf(mx, s_aw[l]);
            __syncthreads();
            if (t < L_ENC) s_aw[t] = expf(s_aw[t] - mx);
            __syncthreads();
            float ssum = 0.f;
            for (int l = 0; l < L_ENC; ++l) ssum += s_aw[l];
            const float inv = 1.f / ssum;

            float4* cat4 = (float4*)s_cat;
            const float4* enc4 = (const float4*)enc;
            cat4[t] = e4[t];
            float4 c = make_float4(0.f, 0.f, 0.f, 0.f);
            for (int l = 0; l < L_ENC; ++l) {
                float a = s_aw[l];
                float4 e = enc4[l * 256 + t];
                c.x += a * e.x; c.y += a * e.y; c.z += a * e.z; c.w += a * e.w;
            }
            cat4[256 + t] = make_float4(c.x * inv, c.y * inv, c.z * inv, c.w * inv);
            __syncthreads();

            for (int k = 0; k < 4; ++k) {
                const int r = blk * 16 + wave * 4 + k;       // 0..1023
                const float4* w4 = (const float4*)(comb_w + (size_t)r * 2048);
                float s = 0.f;
                for (int m = 0; m < 8; ++m) {
                    int j = lane + (m << 6);
                    float4 a = w4[j], b = cat4[j];
                    s += a.x * b.x + a.y * b.y + a.z * b.z + a.w * b.w;
                }
                for (int o = 32; o; o >>= 1) s += __shfl_down(s, o);
                if (lane == 0) ws[WS_X + r] = fmaxf(s + comb_b[r], 0.f);
            }
        }
        // reset the pack slot used NEXT step (safe window: its readers finished
        // before sync1 of this step; its next writers run after sync2+sync3)
        if (blk == 64 && t == 0) pack[(step + 1) & 1] = 0ULL;
        grid.sync();                                         // sync 2

        // ---- P3: gi + gate math -> h_new (blocks 0..255, 4 rows each) ----
        if (blk < 256) {
            float* s_x = s_cat;
            for (int j = t; j < H; j += 256) s_x[j] = ws[WS_X + j];
            __syncthreads();
            const float4* x4 = (const float4*)s_x;
            const int i = blk * 4 + wave;                    // 0..1023
            float g[3];
            for (int p = 0; p < 3; ++p) {
                const float4* w4 = (const float4*)(wih + (size_t)(i + p * H) * H);
                float s = 0.f;
                for (int m = 0; m < 4; ++m) {
                    int j = lane + (m << 6);
                    float4 a = w4[j], b = x4[j];
                    s += a.x * b.x + a.y * b.y + a.z * b.z + a.w * b.w;
                }
                for (int o = 32; o; o >>= 1) s += __shfl_down(s, o);
                g[p] = s;
            }
            if (lane == 0) {
                float gr = g[0] + bih[i]         + ws[WS_GH + i];
                float gz = g[1] + bih[i + H]     + ws[WS_GH + i + H];
                float gn = g[2] + bih[i + 2*H];
                float r = 1.f / (1.f + expf(-gr));
                float z = 1.f / (1.f + expf(-gz));
                float n = tanhf(gn + r * ws[WS_GH + i + 2*H]);
                hnew[i] = (1.f - z) * n + z * hb[i];
            }
        }
        grid.sync();                                         // sync 3

        // ---- P4: logits + packed argmax (blocks 0..507, 99 rows each) ----
        {
            float* s_h = s_cat;
            for (int j = t; j < H; j += 256) s_h[j] = hnew[j];
            __syncthreads();
            const float4* hh = (const float4*)s_h;
            const int base = blk * 99;
            const int end  = min(base + 99, V);
            unsigned long long best = 0ULL;
            for (int r0 = base + wave; r0 < end; r0 += 4) {
                const float4* w4 = (const float4*)(out_w + (size_t)r0 * H);
                float s = 0.f;
                for (int m = 0; m < 4; ++m) {
                    int j = lane + (m << 6);
                    float4 a = w4[j], b = hh[j];
                    s += a.x * b.x + a.y * b.y + a.z * b.z + a.w * b.w;
                }
                for (int o = 32; o; o >>= 1) s += __shfl_xor(s, o);
                s += out_b[r0];
                unsigned int kb = __float_as_uint(s);
                kb = (kb & 0x80000000u) ? ~kb : (kb | 0x80000000u);  // monotone key
                unsigned long long pk =
                    ((unsigned long long)kb << 32) | (unsigned int)(~r0);
                if (pk > best) best = pk;
            }
            if (lane == 0) s_best[wave] = best;
            __syncthreads();
            if (t == 0) {
                unsigned long long b2 = s_best[0];
                if (s_best[1] > b2) b2 = s_best[1];
                if (s_best[2] > b2) b2 = s_best[2];
                if (s_best[3] > b2) b2 = s_best[3];
                if (b2) atomicMax(pack + (step & 1), b2);
            }
        }
        grid.sync();                                         // sync 4

        // ---- decode (every block, identical result; no extra kernel) ----
        if (t == 0) {
            unsigned long long pk = __hip_atomic_load(pack + (step & 1),
                                        __ATOMIC_RELAXED, __HIP_MEMORY_SCOPE_AGENT);
            const int top = (int)(~(unsigned int)(pk & 0xFFFFFFFFu));
            const int done_old = s_done;
            if (blk == 0) out[step] = done_old ? 0 : top;
            s_tok  = top;
            s_done = done_old | (top == 1) | (top == STOP_ID);
            if (!done_old) s_cur ^= 1;                       // h advances iff !done_old
        }
        __syncthreads();
    }
}

// ============================================================================
// Fallback path: original (verified) multi-kernel implementation, used only if
// the cooperative launch is rejected at enqueue time.
// ============================================================================
__global__ __launch_bounds__(1024) void k_init(const int* __restrict__ dec_in,
                                               const float* __restrict__ h0,
                                               float* __restrict__ ws) {
    int t = threadIdx.x;
    ws[WS_H + t] = h0[t];
    if (t == 0) {
        ((int*)(ws + WS_TOK))[0]  = dec_in[0];
        ((int*)(ws + WS_DONE))[0] = 0;
    }
}

__global__ __launch_bounds__(256) void k_pre(const float* __restrict__ embedding,
                                             const float* __restrict__ attn_w,
                                             const float* __restrict__ attn_b,
                                             const float* __restrict__ whh,
                                             const float* __restrict__ bhh,
                                             float* __restrict__ ws) {
    const int wave = threadIdx.x >> 6, lane = threadIdx.x & 63;
    const int tok = ((const int*)(ws + WS_TOK))[0];
    const float4* h4 = (const float4*)(ws + WS_H);
    if (blockIdx.x < 32) {
        const int r = blockIdx.x * 4 + wave;
        const float4* w4 = (const float4*)(attn_w + (size_t)r * 2048);
        const float4* e4 = (const float4*)(embedding + (size_t)tok * H);
        float s = 0.f;
        for (int m = 0; m < 8; ++m) {
            int j = lane + (m << 6);
            float4 a = w4[j];
            float4 c = (j < 256) ? e4[j] : h4[j - 256];
            s += a.x * c.x + a.y * c.y + a.z * c.z + a.w * c.w;
        }
        for (int o = 32; o; o >>= 1) s += __shfl_down(s, o);
        if (lane == 0) ws[WS_ALOG + r] = s + attn_b[r];
    } else {
        const int r = (blockIdx.x - 32) * 4 + wave;
        const float4* w4 = (const float4*)(whh + (size_t)r * H);
        float s = 0.f;
        for (int m = 0; m < 4; ++m) {
            int j = lane + (m << 6);
            float4 a = w4[j], b = h4[j];
            s += a.x * b.x + a.y * b.y + a.z * b.z + a.w * b.w;
        }
        for (int o = 32; o; o >>= 1) s += __shfl_down(s, o);
        if (lane == 0) ws[WS_GH + r] = s + bhh[r];
    }
}

__global__ __launch_bounds__(256) void k_ctx_comb(const float* __restrict__ embedding,
                                                  const float* __restrict__ enc,
                                                  const float* __restrict__ comb_w,
                                                  const float* __restrict__ comb_b,
                                                  float* __restrict__ ws) {
    __shared__ float s_aw[L_ENC];
    __shared__ __align__(16) float s_cat[2048];
    const int t = threadIdx.x;
    const int tok = ((const int*)(ws + WS_TOK))[0];

    if (t < L_ENC) s_aw[t] = ws[WS_ALOG + t];
    __syncthreads();
    float mx = -INFINITY;
    for (int l = 0; l < L_ENC; ++l) mx = fmaxf(mx, s_aw[l]);
    __syncthreads();
    if (t < L_ENC) s_aw[t] = expf(s_aw[t] - mx);
    __syncthreads();
    float ssum = 0.f;
    for (int l = 0; l < L_ENC; ++l) ssum += s_aw[l];
    const float inv = 1.f / ssum;

    float4* cat4 = (float4*)s_cat;
    const float4* e4   = (const float4*)(embedding + (size_t)tok * H);
    const float4* enc4 = (const float4*)enc;
    cat4[t] = e4[t];
    float4 c = make_float4(0.f, 0.f, 0.f, 0.f);
    for (int l = 0; l < L_ENC; ++l) {
        float a = s_aw[l];
        float4 e = enc4[l * 256 + t];
        c.x += a * e.x; c.y += a * e.y; c.z += a * e.z; c.w += a * e.w;
    }
    cat4[256 + t] = make_float4(c.x * inv, c.y * inv, c.z * inv, c.w * inv);
    __syncthreads();

    const int wave = t >> 6, lane = t & 63;
    for (int k = 0; k < 4; ++k) {
        const int r = blockIdx.x * 16 + wave * 4 + k;
        const float4* w4 = (const float4*)(comb_w + (size_t)r * 2048);
        float s = 0.f;
        for (int m = 0; m < 8; ++m) {
            int j = lane + (m << 6);
            float4 a = w4[j], b = cat4[j];
            s += a.x * b.x + a.y * b.y + a.z * b.z + a.w * b.w;
        }
        for (int o = 32; o; o >>= 1) s += __shfl_down(s, o);
        if (lane == 0) ws[WS_X + r] = fmaxf(s + comb_b[r], 0.f);
    }
}

__global__ __launch_bounds__(256) void k_gru(const float* __restrict__ wih,
                                             const float* __restrict__ bih,
                                             float* __restrict__ ws) {
    __shared__ __align__(16) float s_x[H];
    const int t = threadIdx.x, wave = t >> 6, lane = t & 63;
    for (int j = t; j < H; j += 256) s_x[j] = ws[WS_X + j];
    __syncthreads();
    const float4* x4 = (const float4*)s_x;
    const int i = blockIdx.x * 4 + wave;
    float g[3];
    for (int p = 0; p < 3; ++p) {
        const float4* w4 = (const float4*)(wih + (size_t)(i + p * H) * H);
        float s = 0.f;
        for (int m = 0; m < 4; ++m) {
            int j = lane + (m << 6);
            float4 a = w4[j], b = x4[j];
            s += a.x * b.x + a.y * b.y + a.z * b.z + a.w * b.w;
        }
        for (int o = 32; o; o >>= 1) s += __shfl_down(s, o);
        g[p] = s;
    }
    if (lane == 0) {
        float gr = g[0] + bih[i]         + ws[WS_GH + i];
        float gz = g[1] + bih[i + H]     + ws[WS_GH + i + H];
        float gn = g[2] + bih[i + 2*H];
        float r = 1.f / (1.f + expf(-gr));
        float z = 1.f / (1.f + expf(-gz));
        float n = tanhf(gn + r * ws[WS_GH + i + 2*H]);
        ws[WS_HNEW + i] = (1.f - z) * n + z * ws[WS_H + i];
    }
}

__global__ __launch_bounds__(256) void k_logits(const float* __restrict__ out_w,
                                                const float* __restrict__ out_b,
                                                float* __restrict__ ws) {
    __shared__ __align__(16) float s_h[H];
    __shared__ float s_bv[4];
    __shared__ int   s_bi[4];
    const int t = threadIdx.x, wave = t >> 6, lane = t & 63;
    for (int j = t; j < H; j += 256) s_h[j] = ws[WS_HNEW + j];
    __syncthreads();
    const float4* h4 = (const float4*)s_h;
    const int base = blockIdx.x * 99;
    const int end  = min(base + 99, V);
    float bv = -INFINITY; int bi = 0x7fffffff;
    for (int r0 = base + wave; r0 < end; r0 += 4) {
        const float4* w4 = (const float4*)(out_w + (size_t)r0 * H);
        float s = 0.f;
        for (int m = 0; m < 4; ++m) {
            int j = lane + (m << 6);
            float4 a = w4[j], b = h4[j];
            s += a.x * b.x + a.y * b.y + a.z * b.z + a.w * b.w;
        }
        for (int o = 32; o; o >>= 1) s += __shfl_xor(s, o);
        s += out_b[r0];
        if (s > bv) { bv = s; bi = r0; }
    }
    if (lane == 0) { s_bv[wave] = bv; s_bi[wave] = bi; }
    __syncthreads();
    if (t == 0) {
        for (int w2 = 1; w2 < 4; ++w2) {
            float v = s_bv[w2]; int i2 = s_bi[w2];
            if (v > bv || (v == bv && i2 < bi)) { bv = v; bi = i2; }
        }
        ws[WS_PMAX + blockIdx.x] = bv;
        ((int*)(ws + WS_PIDX))[blockIdx.x] = bi;
    }
}

__global__ __launch_bounds__(512) void k_reduce(float* __restrict__ ws,
                                                int* __restrict__ out, int step) {
    __shared__ float s_v[512];
    __shared__ int   s_i[512];
    __shared__ int   s_done;
    const int t = threadIdx.x;
    s_v[t] = (t < NB_OUT) ? ws[WS_PMAX + t] : -INFINITY;
    s_i[t] = (t < NB_OUT) ? ((int*)(ws + WS_PIDX))[t] : 0x7fffffff;
    if (t == 0) s_done = ((int*)(ws + WS_DONE))[0];
    __syncthreads();
    for (int o = 256; o; o >>= 1) {
        if (t < o) {
            float v2 = s_v[t + o]; int i2 = s_i[t + o];
            if (v2 > s_v[t] || (v2 == s_v[t] && i2 < s_i[t])) { s_v[t] = v2; s_i[t] = i2; }
        }
        __syncthreads();
    }
    const int top = s_i[0];
    const int done_old = s_done;
    if (!done_old) {
        ws[WS_H + t]       = ws[WS_HNEW + t];
        ws[WS_H + t + 512] = ws[WS_HNEW + t + 512];
    }
    if (t == 0) {
        out[step] = done_old ? 0 : top;
        ((int*)(ws + WS_TOK))[0]  = top;
        ((int*)(ws + WS_DONE))[0] = done_old | (top == 1) | (top == STOP_ID);
    }
}

extern "C" void kernel_launch(void* const* d_in, const int* in_sizes, int n_in,
                              void* d_out, int out_size, void* d_ws, size_t ws_size,
                              hipStream_t stream) {
    const int*   dec_in = (const int*)  d_in[0];
    const float* h0     = (const float*)d_in[1];
    const float* enc    = (const float*)d_in[2];
    const float* emb    = (const float*)d_in[3];
    const float* attn_w = (const float*)d_in[4];
    const float* attn_b = (const float*)d_in[5];
    const float* comb_w = (const float*)d_in[6];
    const float* comb_b = (const float*)d_in[7];
    const float* wih    = (const float*)d_in[8];
    const float* whh    = (const float*)d_in[9];
    const float* bih    = (const float*)d_in[10];
    const float* bhh    = (const float*)d_in[11];
    const float* out_w  = (const float*)d_in[12];
    const float* out_b  = (const float*)d_in[13];
    float* ws  = (float*)d_ws;
    int*   out = (int*)d_out;

    void* args[16] = { (void*)&dec_in, (void*)&h0, (void*)&enc, (void*)&emb,
                       (void*)&attn_w, (void*)&attn_b, (void*)&comb_w, (void*)&comb_b,
                       (void*)&wih, (void*)&whh, (void*)&bih, (void*)&bhh,
                       (void*)&out_w, (void*)&out_b, (void*)&ws, (void*)&out };

    hipError_t err = hipLaunchCooperativeKernel((const void*)k_decode,
                                                dim3(NBLK), dim3(256),
                                                args, 0, stream);
    if (err != hipSuccess) {
        // fallback: original verified multi-kernel path
        k_init<<<1, 1024, 0, stream>>>(dec_in, h0, ws);
        for (int step = 0; step < STEPS; ++step) {
            k_pre<<<800, 256, 0, stream>>>(emb, attn_w, attn_b, whh, bhh, ws);
            k_ctx_comb<<<64, 256, 0, stream>>>(emb, enc, comb_w, comb_b, ws);
            k_gru<<<256, 256, 0, stream>>>(wih, bih, ws);
            k_logits<<<NB_OUT, 256, 0, stream>>>(out_w, out_b, ws);
            k_reduce<<<1, 512, 0, stream>>>(ws, out, step);
        }
    }
}

// Round 2
// 3333.982 us; speedup vs baseline: 2.8126x; 2.8126x over previous
//
#include <hip/hip_runtime.h>
#include <math.h>

#define H 1024
#define L_ENC 128
#define V 50257
#define STEPS 32
#define STOP_ID 658

// ---- workspace layout (float offsets) ----
#define WS_H     0        // 1024  h ping-pong buf0
#define WS_HNEW  1024     // 1024  h ping-pong buf1
#define WS_GH    2048     // 3072  gh = h @ whh.T + bhh
#define WS_ALOG  5120     // 128   attention logits
#define WS_X     5248     // 1024  x = relu(comb)
#define WS_PMAX  6272     // fallback: per-block argmax value
#define WS_PIDX  6784     // fallback: per-block argmax index
#define WS_TOK   7296     // fallback: current token
#define WS_DONE  7297     // fallback: done flag
#define WS_PACK  6272     // coop: 2 x u64 packed argmax slots (byte 25088)
#define WS_CNT   7424     // coop: barrier arrival counter (monotonic)
#define WS_EPOCH 7456     // coop: barrier epoch (separate cacheline)

#define NB_OUT 508
#define NBLK   512

// ---- fine-grained device-scope (AGENT) accessors: bypass stale per-XCD L2,
// ---- coherent at L3. Weights stay plain/cached (read-only => never stale).
__device__ __forceinline__ float aload(const float* p) {
    return __hip_atomic_load(p, __ATOMIC_RELAXED, __HIP_MEMORY_SCOPE_AGENT);
}
__device__ __forceinline__ void astore(float* p, float v) {
    __hip_atomic_store(p, v, __ATOMIC_RELAXED, __HIP_MEMORY_SCOPE_AGENT);
}

// ---- lightweight grid barrier: monotonic arrivals, no cache-wide fences.
// All payload stores are sc0/sc1 write-through; vmcnt(0) drains them to the
// coherence point before arrival, readers use sc0/sc1 loads => no L2 inval.
__device__ __forceinline__ void grid_bar(unsigned* cnt, unsigned* ep, unsigned target) {
    asm volatile("s_waitcnt vmcnt(0)" ::: "memory");   // per-wave payload drain
    __syncthreads();
    if (threadIdx.x == 0) {
        unsigned old = __hip_atomic_fetch_add(cnt, 1u, __ATOMIC_RELAXED,
                                              __HIP_MEMORY_SCOPE_AGENT);
        if (old == target * (unsigned)NBLK - 1u) {
            __hip_atomic_store(ep, target, __ATOMIC_RELAXED, __HIP_MEMORY_SCOPE_AGENT);
        } else {
            while (__hip_atomic_load(ep, __ATOMIC_RELAXED, __HIP_MEMORY_SCOPE_AGENT) < target)
                __builtin_amdgcn_s_sleep(2);
        }
    }
    __syncthreads();
    asm volatile("" ::: "memory");
}

// ============================================================================
// Persistent kernel, custom barriers (4/step). Per-row FP op order identical
// to the verified multi-kernel version => bit-identical logits/h; argmax via
// packed u64 atomicMax (exact, first-max-index tie-break).
// ============================================================================
__global__ __launch_bounds__(256, 2) void k_decode(
    const int* __restrict__ dec_in, const float* __restrict__ h0,
    const float* __restrict__ enc, const float* __restrict__ embedding,
    const float* __restrict__ attn_w, const float* __restrict__ attn_b,
    const float* __restrict__ comb_w, const float* __restrict__ comb_b,
    const float* __restrict__ wih, const float* __restrict__ whh,
    const float* __restrict__ bih, const float* __restrict__ bhh,
    const float* __restrict__ out_w, const float* __restrict__ out_b,
    float* __restrict__ ws, int* __restrict__ out)
{
    const int t = threadIdx.x, wave = t >> 6, lane = t & 63;
    const int blk = blockIdx.x;

    __shared__ float s_aw[L_ENC];
    __shared__ __align__(16) float s_buf[2048];   // h / cat / x / h_new staging
    __shared__ unsigned long long s_best[4];
    __shared__ int s_tok, s_done, s_cur;

    unsigned long long* const pack = (unsigned long long*)(ws + WS_PACK);
    unsigned* const cnt = (unsigned*)(ws + WS_CNT);
    unsigned* const ep  = (unsigned*)(ws + WS_EPOCH);
    const float4* const s_buf4 = (const float4*)s_buf;

    if (t == 0) { s_tok = dec_in[0]; s_done = 0; s_cur = 0; }
    __syncthreads();
    unsigned bar = 0;

    // ---- P0 (pre-loop): stage h(0) + compute gh(0) (6 rows/block) ----
    for (int j = t; j < H; j += 256) s_buf[j] = aload(ws + WS_H + j);
    __syncthreads();
    for (int q = wave; q < 6; q += 4) {
        const int r = blk * 6 + q;
        const float4* w4 = (const float4*)(whh + (size_t)r * H);
        float s = 0.f;
        for (int m = 0; m < 4; ++m) {
            int j = lane + (m << 6);
            float4 a = w4[j], b = s_buf4[j];
            s += a.x * b.x + a.y * b.y + a.z * b.z + a.w * b.w;
        }
        for (int o = 32; o; o >>= 1) s += __shfl_down(s, o);
        if (lane == 0) astore(ws + WS_GH + r, s + bhh[r]);
    }
    // falls through into step 0's P1; barrier 1 covers gh(0) visibility.

    for (int step = 0; step < STEPS; ++step) {
        const int tok = s_tok;
        float* hb   = ws + (s_cur ? WS_HNEW : WS_H);   // current h
        float* hnew = ws + (s_cur ? WS_H : WS_HNEW);   // candidate slot
        const float4* e4 = (const float4*)(embedding + (size_t)tok * H);

        // ---- P1: attention logits (s_buf holds h: from P0 or P4 staging) ----
        if (blk < 32) {
            const int r = blk * 4 + wave;              // 0..127
            const float4* w4 = (const float4*)(attn_w + (size_t)r * 2048);
            float s = 0.f;
            for (int m = 0; m < 8; ++m) {
                int j = lane + (m << 6);
                float4 a = w4[j];
                float4 c = (j < 256) ? e4[j] : s_buf4[j - 256];
                s += a.x * c.x + a.y * c.y + a.z * c.z + a.w * c.w;
            }
            for (int o = 32; o; o >>= 1) s += __shfl_down(s, o);
            if (lane == 0) astore(ws + WS_ALOG + r, s + attn_b[r]);
        }
        grid_bar(cnt, ep, ++bar);                      // alog (+gh step0) ready

        // ---- P2: softmax + ctx + comb -> x (blocks 0..63) ----
        if (blk < 64) {
            if (t < L_ENC) s_aw[t] = aload(ws + WS_ALOG + t);
            __syncthreads();
            float mx = -INFINITY;
            for (int l = 0; l < L_ENC; ++l) mx = fmaxf(mx, s_aw[l]);
            __syncthreads();
            if (t < L_ENC) s_aw[t] = expf(s_aw[t] - mx);
            __syncthreads();
            float ssum = 0.f;
            for (int l = 0; l < L_ENC; ++l) ssum += s_aw[l];
            const float inv = 1.f / ssum;

            float4* cat4 = (float4*)s_buf;
            const float4* enc4 = (const float4*)enc;
            cat4[t] = e4[t];
            float4 c = make_float4(0.f, 0.f, 0.f, 0.f);
            for (int l = 0; l < L_ENC; ++l) {
                float a = s_aw[l];
                float4 e = enc4[l * 256 + t];
                c.x += a * e.x; c.y += a * e.y; c.z += a * e.z; c.w += a * e.w;
            }
            cat4[256 + t] = make_float4(c.x * inv, c.y * inv, c.z * inv, c.w * inv);
            __syncthreads();

            for (int k = 0; k < 4; ++k) {
                const int r = blk * 16 + wave * 4 + k; // 0..1023
                const float4* w4 = (const float4*)(comb_w + (size_t)r * 2048);
                float s = 0.f;
                for (int m = 0; m < 8; ++m) {
                    int j = lane + (m << 6);
                    float4 a = w4[j], b = ((const float4*)s_buf)[j];
                    s += a.x * b.x + a.y * b.y + a.z * b.z + a.w * b.w;
                }
                for (int o = 32; o; o >>= 1) s += __shfl_down(s, o);
                if (lane == 0) astore(ws + WS_X + r, fmaxf(s + comb_b[r], 0.f));
            }
        }
        if (blk == 64 && t == 0) {   // reset next step's pack slot (safe window)
            __hip_atomic_store(pack + ((step + 1) & 1), 0ULL,
                               __ATOMIC_RELAXED, __HIP_MEMORY_SCOPE_AGENT);
        }
        grid_bar(cnt, ep, ++bar);                      // x ready

        // ---- P3: gi + gate math -> h_new (blocks 0..255) ----
        if (blk < 256) {
            for (int j = t; j < H; j += 256) s_buf[j] = aload(ws + WS_X + j);
            __syncthreads();
            const int i = blk * 4 + wave;              // 0..1023
            float g[3];
            for (int p = 0; p < 3; ++p) {
                const float4* w4 = (const float4*)(wih + (size_t)(i + p * H) * H);
                float s = 0.f;
                for (int m = 0; m < 4; ++m) {
                    int j = lane + (m << 6);
                    float4 a = w4[j], b = s_buf4[j];
                    s += a.x * b.x + a.y * b.y + a.z * b.z + a.w * b.w;
                }
                for (int o = 32; o; o >>= 1) s += __shfl_down(s, o);
                g[p] = s;
            }
            if (lane == 0) {
                float gr = g[0] + bih[i]         + aload(ws + WS_GH + i);
                float gz = g[1] + bih[i + H]     + aload(ws + WS_GH + i + H);
                float gn = g[2] + bih[i + 2*H];
                float r = 1.f / (1.f + expf(-gr));
                float z = 1.f / (1.f + expf(-gz));
                float n = tanhf(gn + r * aload(ws + WS_GH + i + 2*H));
                astore(hnew + i, (1.f - z) * n + z * aload(hb + i));
            }
        }
        grid_bar(cnt, ep, ++bar);                      // h_new ready

        // ---- P4: stage h_new; gh(step+1) (6 rows/blk); logits+argmax ----
        {
            for (int j = t; j < H; j += 256) s_buf[j] = aload(hnew + j);
            __syncthreads();
            // gh for next step (h(next) == h_new, already in s_buf)
            for (int q = wave; q < 6; q += 4) {
                const int r = blk * 6 + q;
                const float4* w4 = (const float4*)(whh + (size_t)r * H);
                float s = 0.f;
                for (int m = 0; m < 4; ++m) {
                    int j = lane + (m << 6);
                    float4 a = w4[j], b = s_buf4[j];
                    s += a.x * b.x + a.y * b.y + a.z * b.z + a.w * b.w;
                }
                for (int o = 32; o; o >>= 1) s += __shfl_down(s, o);
                if (lane == 0) astore(ws + WS_GH + r, s + bhh[r]);
            }
            // logits rows, 2-row unroll for MLP
            const int base = blk * 99;
            const int end  = min(base + 99, V);
            unsigned long long best = 0ULL;
            for (int r = base + wave * 2; r < end; r += 8) {
                const int r1 = r + 1;
                const bool has1 = (r1 < end);
                const float4* w0 = (const float4*)(out_w + (size_t)r * H);
                const float4* w1 = (const float4*)(out_w + (size_t)(has1 ? r1 : r) * H);
                float sa = 0.f, sb = 0.f;
                for (int m = 0; m < 4; ++m) {
                    int j = lane + (m << 6);
                    float4 a0 = w0[j], a1 = w1[j], b = s_buf4[j];
                    sa += a0.x * b.x + a0.y * b.y + a0.z * b.z + a0.w * b.w;
                    sb += a1.x * b.x + a1.y * b.y + a1.z * b.z + a1.w * b.w;
                }
                for (int o = 32; o; o >>= 1) {
                    sa += __shfl_xor(sa, o);
                    sb += __shfl_xor(sb, o);
                }
                sa += out_b[r];
                unsigned ka = __float_as_uint(sa);
                ka = (ka & 0x80000000u) ? ~ka : (ka | 0x80000000u);
                unsigned long long pa = ((unsigned long long)ka << 32) | (unsigned)(~r);
                if (pa > best) best = pa;
                if (has1) {
                    sb += out_b[r1];
                    unsigned kb = __float_as_uint(sb);
                    kb = (kb & 0x80000000u) ? ~kb : (kb | 0x80000000u);
                    unsigned long long pb = ((unsigned long long)kb << 32) | (unsigned)(~r1);
                    if (pb > best) best = pb;
                }
            }
            if (lane == 0) s_best[wave] = best;
            __syncthreads();
            if (t == 0) {
                unsigned long long b2 = s_best[0];
                if (s_best[1] > b2) b2 = s_best[1];
                if (s_best[2] > b2) b2 = s_best[2];
                if (s_best[3] > b2) b2 = s_best[3];
                if (b2) atomicMax(pack + (step & 1), b2);
            }
        }
        grid_bar(cnt, ep, ++bar);                      // argmax ready

        // ---- decode (replicated; identical in every block) ----
        if (t == 0) {
            unsigned long long pk = __hip_atomic_load(pack + (step & 1),
                                        __ATOMIC_RELAXED, __HIP_MEMORY_SCOPE_AGENT);
            const int top = (int)(~(unsigned)(pk & 0xFFFFFFFFu));
            if (blk == 0) out[step] = top;             // done always 0 here
            s_tok  = top;
            s_done = (top == 1) | (top == STOP_ID);
            s_cur ^= 1;
        }
        __syncthreads();
        if (s_done) {   // all outputs after stop are 0; internal state unobservable
            if (blk == 0)
                for (int j = step + 1 + t; j < STEPS; j += 256) out[j] = 0;
            break;
        }
    }
}

// ============================================================================
// init kernel (one launch): h0 copy + barrier/argmax/fallback state
// ============================================================================
__global__ __launch_bounds__(1024) void k_init(const int* __restrict__ dec_in,
                                               const float* __restrict__ h0,
                                               float* __restrict__ ws) {
    int t = threadIdx.x;
    ws[WS_H + t] = h0[t];
    if (t == 0) {
        ((int*)(ws + WS_TOK))[0]  = dec_in[0];
        ((int*)(ws + WS_DONE))[0] = 0;
        ((unsigned long long*)(ws + WS_PACK))[0] = 0ULL;
        ((unsigned long long*)(ws + WS_PACK))[1] = 0ULL;
        ((unsigned*)(ws + WS_CNT))[0]   = 0u;
        ((unsigned*)(ws + WS_EPOCH))[0] = 0u;
    }
}

// ============================================================================
// Fallback path (verified multi-kernel) — used only if coop launch fails.
// ============================================================================
__global__ __launch_bounds__(256) void k_pre(const float* __restrict__ embedding,
                                             const float* __restrict__ attn_w,
                                             const float* __restrict__ attn_b,
                                             const float* __restrict__ whh,
                                             const float* __restrict__ bhh,
                                             float* __restrict__ ws) {
    const int wave = threadIdx.x >> 6, lane = threadIdx.x & 63;
    const int tok = ((const int*)(ws + WS_TOK))[0];
    const float4* h4 = (const float4*)(ws + WS_H);
    if (blockIdx.x < 32) {
        const int r = blockIdx.x * 4 + wave;
        const float4* w4 = (const float4*)(attn_w + (size_t)r * 2048);
        const float4* e4 = (const float4*)(embedding + (size_t)tok * H);
        float s = 0.f;
        for (int m = 0; m < 8; ++m) {
            int j = lane + (m << 6);
            float4 a = w4[j];
            float4 c = (j < 256) ? e4[j] : h4[j - 256];
            s += a.x * c.x + a.y * c.y + a.z * c.z + a.w * c.w;
        }
        for (int o = 32; o; o >>= 1) s += __shfl_down(s, o);
        if (lane == 0) ws[WS_ALOG + r] = s + attn_b[r];
    } else {
        const int r = (blockIdx.x - 32) * 4 + wave;
        const float4* w4 = (const float4*)(whh + (size_t)r * H);
        float s = 0.f;
        for (int m = 0; m < 4; ++m) {
            int j = lane + (m << 6);
            float4 a = w4[j], b = h4[j];
            s += a.x * b.x + a.y * b.y + a.z * b.z + a.w * b.w;
        }
        for (int o = 32; o; o >>= 1) s += __shfl_down(s, o);
        if (lane == 0) ws[WS_GH + r] = s + bhh[r];
    }
}

__global__ __launch_bounds__(256) void k_ctx_comb(const float* __restrict__ embedding,
                                                  const float* __restrict__ enc,
                                                  const float* __restrict__ comb_w,
                                                  const float* __restrict__ comb_b,
                                                  float* __restrict__ ws) {
    __shared__ float s_aw[L_ENC];
    __shared__ __align__(16) float s_cat[2048];
    const int t = threadIdx.x;
    const int tok = ((const int*)(ws + WS_TOK))[0];

    if (t < L_ENC) s_aw[t] = ws[WS_ALOG + t];
    __syncthreads();
    float mx = -INFINITY;
    for (int l = 0; l < L_ENC; ++l) mx = fmaxf(mx, s_aw[l]);
    __syncthreads();
    if (t < L_ENC) s_aw[t] = expf(s_aw[t] - mx);
    __syncthreads();
    float ssum = 0.f;
    for (int l = 0; l < L_ENC; ++l) ssum += s_aw[l];
    const float inv = 1.f / ssum;

    float4* cat4 = (float4*)s_cat;
    const float4* e4   = (const float4*)(embedding + (size_t)tok * H);
    const float4* enc4 = (const float4*)enc;
    cat4[t] = e4[t];
    float4 c = make_float4(0.f, 0.f, 0.f, 0.f);
    for (int l = 0; l < L_ENC; ++l) {
        float a = s_aw[l];
        float4 e = enc4[l * 256 + t];
        c.x += a * e.x; c.y += a * e.y; c.z += a * e.z; c.w += a * e.w;
    }
    cat4[256 + t] = make_float4(c.x * inv, c.y * inv, c.z * inv, c.w * inv);
    __syncthreads();

    const int wave = t >> 6, lane = t & 63;
    for (int k = 0; k < 4; ++k) {
        const int r = blockIdx.x * 16 + wave * 4 + k;
        const float4* w4 = (const float4*)(comb_w + (size_t)r * 2048);
        float s = 0.f;
        for (int m = 0; m < 8; ++m) {
            int j = lane + (m << 6);
            float4 a = w4[j], b = cat4[j];
            s += a.x * b.x + a.y * b.y + a.z * b.z + a.w * b.w;
        }
        for (int o = 32; o; o >>= 1) s += __shfl_down(s, o);
        if (lane == 0) ws[WS_X + r] = fmaxf(s + comb_b[r], 0.f);
    }
}

__global__ __launch_bounds__(256) void k_gru(const float* __restrict__ wih,
                                             const float* __restrict__ bih,
                                             float* __restrict__ ws) {
    __shared__ __align__(16) float s_x[H];
    const int t = threadIdx.x, wave = t >> 6, lane = t & 63;
    for (int j = t; j < H; j += 256) s_x[j] = ws[WS_X + j];
    __syncthreads();
    const float4* x4 = (const float4*)s_x;
    const int i = blockIdx.x * 4 + wave;
    float g[3];
    for (int p = 0; p < 3; ++p) {
        const float4* w4 = (const float4*)(wih + (size_t)(i + p * H) * H);
        float s = 0.f;
        for (int m = 0; m < 4; ++m) {
            int j = lane + (m << 6);
            float4 a = w4[j], b = x4[j];
            s += a.x * b.x + a.y * b.y + a.z * b.z + a.w * b.w;
        }
        for (int o = 32; o; o >>= 1) s += __shfl_down(s, o);
        g[p] = s;
    }
    if (lane == 0) {
        float gr = g[0] + bih[i]         + ws[WS_GH + i];
        float gz = g[1] + bih[i + H]     + ws[WS_GH + i + H];
        float gn = g[2] + bih[i + 2*H];
        float r = 1.f / (1.f + expf(-gr));
        float z = 1.f / (1.f + expf(-gz));
        float n = tanhf(gn + r * ws[WS_GH + i + 2*H]);
        ws[WS_HNEW + i] = (1.f - z) * n + z * ws[WS_H + i];
    }
}

__global__ __launch_bounds__(256) void k_logits(const float* __restrict__ out_w,
                                                const float* __restrict__ out_b,
                                                float* __restrict__ ws) {
    __shared__ __align__(16) float s_h[H];
    __shared__ float s_bv[4];
    __shared__ int   s_bi[4];
    const int t = threadIdx.x, wave = t >> 6, lane = t & 63;
    for (int j = t; j < H; j += 256) s_h[j] = ws[WS_HNEW + j];
    __syncthreads();
    const float4* h4 = (const float4*)s_h;
    const int base = blockIdx.x * 99;
    const int end  = min(base + 99, V);
    float bv = -INFINITY; int bi = 0x7fffffff;
    for (int r0 = base + wave; r0 < end; r0 += 4) {
        const float4* w4 = (const float4*)(out_w + (size_t)r0 * H);
        float s = 0.f;
        for (int m = 0; m < 4; ++m) {
            int j = lane + (m << 6);
            float4 a = w4[j], b = h4[j];
            s += a.x * b.x + a.y * b.y + a.z * b.z + a.w * b.w;
        }
        for (int o = 32; o; o >>= 1) s += __shfl_xor(s, o);
        s += out_b[r0];
        if (s > bv) { bv = s; bi = r0; }
    }
    if (lane == 0) { s_bv[wave] = bv; s_bi[wave] = bi; }
    __syncthreads();
    if (t == 0) {
        for (int w2 = 1; w2 < 4; ++w2) {
            float v = s_bv[w2]; int i2 = s_bi[w2];
            if (v > bv || (v == bv && i2 < bi)) { bv = v; bi = i2; }
        }
        ws[WS_PMAX + blockIdx.x] = bv;
        ((int*)(ws + WS_PIDX))[blockIdx.x] = bi;
    }
}

__global__ __launch_bounds__(512) void k_reduce(float* __restrict__ ws,
                                                int* __restrict__ out, int step) {
    __shared__ float s_v[512];
    __shared__ int   s_i[512];
    __shared__ int   s_done;
    const int t = threadIdx.x;
    s_v[t] = (t < NB_OUT) ? ws[WS_PMAX + t] : -INFINITY;
    s_i[t] = (t < NB_OUT) ? ((int*)(ws + WS_PIDX))[t] : 0x7fffffff;
    if (t == 0) s_done = ((int*)(ws + WS_DONE))[0];
    __syncthreads();
    for (int o = 256; o; o >>= 1) {
        if (t < o) {
            float v2 = s_v[t + o]; int i2 = s_i[t + o];
            if (v2 > s_v[t] || (v2 == s_v[t] && i2 < s_i[t])) { s_v[t] = v2; s_i[t] = i2; }
        }
        __syncthreads();
    }
    const int top = s_i[0];
    const int done_old = s_done;
    if (!done_old) {
        ws[WS_H + t]       = ws[WS_HNEW + t];
        ws[WS_H + t + 512] = ws[WS_HNEW + t + 512];
    }
    if (t == 0) {
        out[step] = done_old ? 0 : top;
        ((int*)(ws + WS_TOK))[0]  = top;
        ((int*)(ws + WS_DONE))[0] = done_old | (top == 1) | (top == STOP_ID);
    }
}

extern "C" void kernel_launch(void* const* d_in, const int* in_sizes, int n_in,
                              void* d_out, int out_size, void* d_ws, size_t ws_size,
                              hipStream_t stream) {
    const int*   dec_in = (const int*)  d_in[0];
    const float* h0     = (const float*)d_in[1];
    const float* enc    = (const float*)d_in[2];
    const float* emb    = (const float*)d_in[3];
    const float* attn_w = (const float*)d_in[4];
    const float* attn_b = (const float*)d_in[5];
    const float* comb_w = (const float*)d_in[6];
    const float* comb_b = (const float*)d_in[7];
    const float* wih    = (const float*)d_in[8];
    const float* whh    = (const float*)d_in[9];
    const float* bih    = (const float*)d_in[10];
    const float* bhh    = (const float*)d_in[11];
    const float* out_w  = (const float*)d_in[12];
    const float* out_b  = (const float*)d_in[13];
    float* ws  = (float*)d_ws;
    int*   out = (int*)d_out;

    k_init<<<1, 1024, 0, stream>>>(dec_in, h0, ws);

    void* args[16] = { (void*)&dec_in, (void*)&h0, (void*)&enc, (void*)&emb,
                       (void*)&attn_w, (void*)&attn_b, (void*)&comb_w, (void*)&comb_b,
                       (void*)&wih, (void*)&whh, (void*)&bih, (void*)&bhh,
                       (void*)&out_w, (void*)&out_b, (void*)&ws, (void*)&out };

    hipError_t err = hipLaunchCooperativeKernel((const void*)k_decode,
                                                dim3(NBLK), dim3(256),
                                                args, 0, stream);
    if (err != hipSuccess) {
        // fallback: original verified multi-kernel path
        for (int step = 0; step < STEPS; ++step) {
            k_pre<<<800, 256, 0, stream>>>(emb, attn_w, attn_b, whh, bhh, ws);
            k_ctx_comb<<<64, 256, 0, stream>>>(emb, enc, comb_w, comb_b, ws);
            k_gru<<<256, 256, 0, stream>>>(wih, bih, ws);
            k_logits<<<NB_OUT, 256, 0, stream>>>(out_w, out_b, ws);
            k_reduce<<<1, 512, 0, stream>>>(ws, out, step);
        }
    }
}